// Round 20
// baseline (1403.230 us; speedup 1.0000x reference)
//
#include <hip/hip_runtime.h>
#include <hip/hip_bf16.h>

#define D_DIM 1024
#define NTOK 267735
#define NEXT_ 267737   // + 2 cluster columns
#define HEADN 20000

typedef __attribute__((ext_vector_type(8))) short bf16x8;
typedef __attribute__((ext_vector_type(4))) float f32x4;
typedef __attribute__((ext_vector_type(4))) unsigned uint4v;

__device__ __forceinline__ int seg_of(int c){
  if (c < HEADN)  return 0;
  if (c < 20008)  return 1;
  if (c < 20016)  return 2;
  if (c < 200000) return 3;
  if (c < NTOK)   return 4;
  return 0; // cluster columns belong to head softmax
}

__device__ __forceinline__ unsigned pack2(float x, float y){
  __hip_bfloat16 a = __float2bfloat16(x);
  __hip_bfloat16 b = __float2bfloat16(y);
  unsigned short ua = *reinterpret_cast<unsigned short*>(&a);
  unsigned short ub = *reinterpret_cast<unsigned short*>(&b);
  return (unsigned)ua | ((unsigned)ub << 16);
}

#define BM 256
#define BN 128
#define BK 32
#define NTHREADS 512
#define KSTEPS (D_DIM/BK)   // 32
#define NCOLT 2092          // ceil(NEXT_/128)
#define NBLK 8384           // 8 XCD * 1048 (16 dead pad blocks)

#define APRIME_OFF 32768                      // byte offset of A' in ws
#define APRIME_BYTES (1024*1024*2)            // 2 MB bf16 fragment-ordered hidden

// direct global->LDS (16B/lane). Dest is wave-uniform base + lane*16 (m104);
// source address is per-lane.
__device__ __forceinline__ void stage16(const float* g, unsigned short* l){
  __builtin_amdgcn_global_load_lds(
      (const __attribute__((address_space(1))) void*)g,
      (__attribute__((address_space(3))) void*)l, 16, 0, 0);
}

// packed fp32x2 -> bf16x2 (single VALU op). Low half = x.
#define CVTPK(d, x, y) asm("v_cvt_pk_bf16_f32 %0, %1, %2" : "=v"(d) : "v"(x), "v"(y))

// Convert hidden (1024x1024 f32) -> A' bf16 in MFMA-fragment order:
// A'[rb(64)][kc(128)][r16(16)][e(8)]; wave frag load = 1024 contiguous bytes.
__global__ void prep_convert(const float* __restrict__ hidden,
                             unsigned short* __restrict__ Ap)
{
  int t = blockIdx.x * blockDim.x + threadIdx.x;   // 0..131071
  int r16 = t & 15, kc = (t >> 4) & 127, rb = t >> 11;
  const float4* src = reinterpret_cast<const float4*>(hidden + ((size_t)(rb*16 + r16) * D_DIM + kc*8));
  float4 x = src[0], y = src[1];
  uint4 o;
  o.x = pack2(x.x, x.y); o.y = pack2(x.z, x.w);
  o.z = pack2(y.x, y.y); o.w = pack2(y.z, y.w);
  reinterpret_cast<uint4*>(Ap)[t] = o;             // dst = t*16B: fully coalesced
}

// Per-(row, segment) sum of exp(logit + bias) into accg[row*8 + seg].
// R20 = R16 datapath with a 4-slot LDS RING + counted-vmcnt flight:
//  - lsB = 4 x 16 KB ring (offset (kt&3)*8192, no pointer-select regs;
//    unroll-4 folds slot offsets to immediates). LDS 64 KB/block, 2 blocks/CU.
//  - per step: A-frag loads first (fence), STAGE(kt+2) into slot (kt+2)&3,
//    B-frags + 16 MFMA, then RAW s_barrier (lgkmcnt only — NO vmcnt(0) drain).
//  - correctness (vmcnt retires in issue order): the compiler's own A-frag
//    wait at step kt is vmcnt(2), which necessarily retires stage(kt+1)
//    (issued one step earlier) -> slot kt+1 is complete before the barrier.
//    WAR: slot (kt+2)&3 was last read 2 barriers ago.
//  Stages fly ~2 full steps (>= HBM miss latency); the 32 per-step vmcnt(0)
//  drains are gone. Same ~60-reg class (the 128-reg cliff killed all deeper
//  register-based pipelines: R4/R6/R7/R11/R14). Everything else = R16:
//  fp32 B DMA staging with source-XOR involution, consumer cvt_pk, A'-direct
//  from L2 (R8), 16x16x32 MFMA (R17), XCD remap (R5).
__global__ __launch_bounds__(NTHREADS, 1) void gemm_lse_adir(
    const unsigned short* __restrict__ Ap, const float* __restrict__ W,
    const float* __restrict__ bias,   const float* __restrict__ cw,
    const float* __restrict__ cb,     float* __restrict__ accg)
{
  const int b = blockIdx.x;
  const int k8 = b & 7;                // XCD slot
  const int sq_ = b >> 3;              // sequence within XCD
  const int xb = sq_ & 3;              // row-block 0..3 (sharers adjacent)
  const int yb = (sq_ >> 2) * 8 + k8;  // col-strip
  if (yb >= NCOLT) return;             // pad blocks

  // 4-slot ring: each slot = one K-step fp32 B tile [h(2)][row(128)][16f] = 16 KB.
  __shared__ unsigned short lsB[4 * 8192];   // 64 KB

  const int tid = threadIdx.x;
  const int rowBase = xb * BM;
  const int colBase = yb * BN;

  const int lane = tid & 63;
  const int wv = tid >> 6;
  const int wm = wv >> 1;   // 0..3 : 64-row slab
  const int wn = wv & 1;    // 0..1 : 64-col slab
  const int q  = lane >> 4; // k-chunk
  const int r16 = lane & 15;

  // ---- B stage source pointer: wave wv covers rows wv*16..+16; lane ->
  // (row_local = lane>>2, dest chunk = lane&3); source chunk XOR'd (involution
  // with the read).
  const float* sp;
  {
    int srow = wv*16 + (lane >> 2);
    int c    = (lane & 3) ^ ((srow >> 1) & 3);
    int col  = colBase + srow;
    const float* base = (col < NTOK)  ? (W  + (size_t)col * D_DIM)
                      : (col < NEXT_) ? (cw + (size_t)(col - NTOK) * D_DIM) : W;
    sp = base + c*4;
  }
  const int dstH0 = wv*512;            // h=0 region within a slot (ushort units)
  const int dstH1 = 4096 + wv*512;     // h=1 region within a slot

  // stage K-step kn into ring slot (kn&3)
#define STAGE_R(kn) do{ \
    stage16(sp + (kn)*BK,      &lsB[((kn)&3)*8192 + dstH0]); \
    stage16(sp + (kn)*BK + 16, &lsB[((kn)&3)*8192 + dstH1]); }while(0)

  // raw barrier: lgkmcnt only — global_load_lds (vmcnt) stays in flight
#define BARRAW() do{ asm volatile("s_waitcnt lgkmcnt(0)" ::: "memory"); \
                     __builtin_amdgcn_s_barrier(); }while(0)

  // ---- consumer B-fragment offsets (ushort units, within one slot) ----
  int loO[4], hiO[4];
#pragma unroll
  for (int j=0;j<4;++j){
    int row = wn*64 + j*16 + r16;
    int swz = (row >> 1) & 3;
    int h   = q >> 1;
    loO[j] = h*4096 + row*32 + (((2*q  ) & 3) ^ swz)*8;
    hiO[j] = h*4096 + row*32 + (((2*q+1) & 3) ^ swz)*8;
  }

  // A' fragment pointers (ushort units): frag i at a_i + kt*512
  const unsigned short* a0 = Ap + (size_t)(xb*16 + wm*4 + 0)*16384 + q*128 + r16*8;
  const unsigned short* a1 = Ap + (size_t)(xb*16 + wm*4 + 1)*16384 + q*128 + r16*8;
  const unsigned short* a2 = Ap + (size_t)(xb*16 + wm*4 + 2)*16384 + q*128 + r16*8;
  const unsigned short* a3 = Ap + (size_t)(xb*16 + wm*4 + 3)*16384 + q*128 + r16*8;

  f32x4 acc[4][4];
#pragma unroll
  for (int i=0;i<4;++i)
#pragma unroll
    for (int j=0;j<4;++j) acc[i][j] = (f32x4){0.f,0.f,0.f,0.f};

#define BFRAG(Lp, j, out) { \
    float4 lo = *reinterpret_cast<const float4*>(&Lp[loO[j]]); \
    float4 hi = *reinterpret_cast<const float4*>(&Lp[hiO[j]]); \
    unsigned u0,u1,u2,u3; \
    CVTPK(u0, lo.x, lo.y); CVTPK(u1, lo.z, lo.w); \
    CVTPK(u2, hi.x, hi.y); CVTPK(u3, hi.z, hi.w); \
    uint4v uu; uu.x=u0; uu.y=u1; uu.z=u2; uu.w=u3; \
    out = __builtin_bit_cast(bf16x8, uu); }

  // ---- prologue: stage K-steps 0 and 1; full drain once ----
  STAGE_R(0);
  STAGE_R(1);
  __syncthreads();   // vmcnt(0)+lgkmcnt(0): slots 0,1 published

#pragma unroll 4
  for (int kt = 0; kt < KSTEPS; ++kt){
    const unsigned short* Lp = lsB + (kt & 3)*8192;

    // A frags first (oldest VMEM of this step): the compiler's wait for
    // these (vmcnt(2)) also retires stage(kt+1) -> slot kt+1 provably done.
    bf16x8 af0 = *reinterpret_cast<const bf16x8*>(a0 + kt*512);
    bf16x8 af1 = *reinterpret_cast<const bf16x8*>(a1 + kt*512);
    bf16x8 af2 = *reinterpret_cast<const bf16x8*>(a2 + kt*512);
    bf16x8 af3 = *reinterpret_cast<const bf16x8*>(a3 + kt*512);
    __builtin_amdgcn_sched_barrier(0);   // pin: A loads issue before stages

    if (kt + 2 < KSTEPS) STAGE_R(kt+2);  // newest VMEM: ~2 steps of flight

    bf16x8 b0, b1, b2, b3;
    BFRAG(Lp, 0, b0); BFRAG(Lp, 1, b1); BFRAG(Lp, 2, b2); BFRAG(Lp, 3, b3);

    acc[0][0] = __builtin_amdgcn_mfma_f32_16x16x32_bf16(af0, b0, acc[0][0], 0,0,0);
    acc[0][1] = __builtin_amdgcn_mfma_f32_16x16x32_bf16(af0, b1, acc[0][1], 0,0,0);
    acc[0][2] = __builtin_amdgcn_mfma_f32_16x16x32_bf16(af0, b2, acc[0][2], 0,0,0);
    acc[0][3] = __builtin_amdgcn_mfma_f32_16x16x32_bf16(af0, b3, acc[0][3], 0,0,0);
    acc[1][0] = __builtin_amdgcn_mfma_f32_16x16x32_bf16(af1, b0, acc[1][0], 0,0,0);
    acc[1][1] = __builtin_amdgcn_mfma_f32_16x16x32_bf16(af1, b1, acc[1][1], 0,0,0);
    acc[1][2] = __builtin_amdgcn_mfma_f32_16x16x32_bf16(af1, b2, acc[1][2], 0,0,0);
    acc[1][3] = __builtin_amdgcn_mfma_f32_16x16x32_bf16(af1, b3, acc[1][3], 0,0,0);
    acc[2][0] = __builtin_amdgcn_mfma_f32_16x16x32_bf16(af2, b0, acc[2][0], 0,0,0);
    acc[2][1] = __builtin_amdgcn_mfma_f32_16x16x32_bf16(af2, b1, acc[2][1], 0,0,0);
    acc[2][2] = __builtin_amdgcn_mfma_f32_16x16x32_bf16(af2, b2, acc[2][2], 0,0,0);
    acc[2][3] = __builtin_amdgcn_mfma_f32_16x16x32_bf16(af2, b3, acc[2][3], 0,0,0);
    acc[3][0] = __builtin_amdgcn_mfma_f32_16x16x32_bf16(af3, b0, acc[3][0], 0,0,0);
    acc[3][1] = __builtin_amdgcn_mfma_f32_16x16x32_bf16(af3, b1, acc[3][1], 0,0,0);
    acc[3][2] = __builtin_amdgcn_mfma_f32_16x16x32_bf16(af3, b2, acc[3][2], 0,0,0);
    acc[3][3] = __builtin_amdgcn_mfma_f32_16x16x32_bf16(af3, b3, acc[3][3], 0,0,0);

    BARRAW();   // raw: stages for kt+2 stay in flight across the barrier
  }

  // ---- fused epilogue: exp + segmented reduce + atomic ----
  int sq[4]; float bq[4];
#pragma unroll
  for (int f=0; f<4; ++f){
    int c = colBase + wn*64 + f*16 + r16;
    if (c < NTOK)       { sq[f] = seg_of(c); bq[f] = bias[c]; }
    else if (c < NEXT_) { sq[f] = 0;         bq[f] = cb[c - NTOK]; }
    else                { sq[f] = -1;        bq[f] = 0.f; }
  }
  int sfirst = seg_of(colBase);
  int clast  = colBase + BN - 1; if (clast > NEXT_-1) clast = NEXT_-1;
  int slast  = seg_of(clast);
  int smin = sfirst, smax = slast;
  if (slast < sfirst){ smin = 0; smax = 4; }   // wrap tile at N_TOKEN boundary

#pragma unroll
  for (int i=0;i<4;++i){
#pragma unroll
    for (int r=0;r<4;++r){
      float e[4];
#pragma unroll
      for (int f=0;f<4;++f) e[f] = __expf(acc[i][f][r] + bq[f]);
      int rowg = rowBase + wm*64 + i*16 + (lane>>4)*4 + r;   // C/D: row=(l>>4)*4+reg
      for (int s2 = smin; s2 <= smax; ++s2){
        float p2 = 0.f;
#pragma unroll
        for (int f=0;f<4;++f) p2 += (sq[f]==s2) ? e[f] : 0.f;
#pragma unroll
        for (int off=1; off<16; off<<=1) p2 += __shfl_xor(p2, off, 16);
        if ((lane & 15) == 0 && p2 != 0.f) atomicAdd(&accg[rowg*8 + s2], p2);
      }
    }
  }
}

// One wave per row: target logit + routing logit + final nll.
__global__ __launch_bounds__(256) void finalize_kernel(
    const float* __restrict__ hidden, const int* __restrict__ target,
    const float* __restrict__ W,      const float* __restrict__ bias,
    const float* __restrict__ cw,     const float* __restrict__ cb,
    const float* __restrict__ accg,   float* __restrict__ out)
{
  const int row  = blockIdx.x * 4 + (threadIdx.x >> 6);
  const int lane = threadIdx.x & 63;
  const int t = target[row];

  const float4* h4 = reinterpret_cast<const float4*>(hidden + (size_t)row * D_DIM);
  const float4* w1 = reinterpret_cast<const float4*>(W + (size_t)t * D_DIM);
  int s = 0; const float* jraw = W; float jb = 0.f;
  if (t >= HEADN){
    if      (t < 20008)  { s=1; jraw = W;          jb = bias[0]; }  // j = 0
    else if (t < 20016)  { s=2; jraw = W + D_DIM;  jb = bias[1]; }  // j = 1
    else if (t < 200000) { s=3; jraw = cw + D_DIM; jb = cb[1];   }  // j = 20001 -> cluster 1
    else                 { s=4; jraw = cw;         jb = cb[0];   }  // j = 20000 -> cluster 0
  }
  const float4* w2 = reinterpret_cast<const float4*>(jraw);

  float p1 = 0.f, p2 = 0.f;
#pragma unroll
  for (int j=0;j<4;++j){
    float4 hv = h4[lane + 64*j];
    float4 av = w1[lane + 64*j];
    float4 bv = w2[lane + 64*j];
    p1 += hv.x*av.x + hv.y*av.y + hv.z*av.z + hv.w*av.w;
    p2 += hv.x*bv.x + hv.y*bv.y + hv.z*bv.z + hv.w*bv.w;
  }
#pragma unroll
  for (int off=32; off; off>>=1){
    p1 += __shfl_xor(p1, off, 64);
    p2 += __shfl_xor(p2, off, 64);
  }

  if (lane == 0){
    float lseH = __logf(accg[row*8 + 0]);
    float nll;
    if (t < HEADN){
      nll = -(p1 + bias[t] - lseH);
    } else {
      float lseS = __logf(accg[row*8 + s]);
      nll = -((p2 + jb - lseH) + (p1 + bias[t] - lseS));
    }
    out[row] = nll;
  }
}

extern "C" void kernel_launch(void* const* d_in, const int* in_sizes, int n_in,
                              void* d_out, int out_size, void* d_ws, size_t ws_size,
                              hipStream_t stream)
{
  const float* hidden = (const float*)d_in[0];
  const int*   target = (const int*)  d_in[1];
  const float* W      = (const float*)d_in[2];
  const float* bias   = (const float*)d_in[3];
  const float* cw     = (const float*)d_in[4];
  const float* cb     = (const float*)d_in[5];
  float* out  = (float*)d_out;
  float* accg = (float*)d_ws;          // [1024][8] fp32 sum-of-exp accumulators
  unsigned short* Ap = (unsigned short*)((char*)d_ws + APRIME_OFF);

  hipMemsetAsync(accg, 0, 1024*8*sizeof(float), stream);

  prep_convert<<<512, 256, 0, stream>>>(hidden, Ap);
  gemm_lse_adir<<<NBLK, NTHREADS, 0, stream>>>(Ap, W, bias, cw, cb, accg);
  finalize_kernel<<<256, 256, 0, stream>>>(hidden, target, W, bias, cw, cb, accg, out);
}

// Round 21
// 820.324 us; speedup vs baseline: 1.7106x; 1.7106x over previous
//
#include <hip/hip_runtime.h>
#include <hip/hip_bf16.h>

#define D_DIM 1024
#define NTOK 267735
#define NEXT_ 267737   // + 2 cluster columns
#define HEADN 20000

typedef __attribute__((ext_vector_type(8))) short bf16x8;
typedef __attribute__((ext_vector_type(4))) float f32x4;
typedef __attribute__((ext_vector_type(4))) unsigned uint4v;

__device__ __forceinline__ int seg_of(int c){
  if (c < HEADN)  return 0;
  if (c < 20008)  return 1;
  if (c < 20016)  return 2;
  if (c < 200000) return 3;
  if (c < NTOK)   return 4;
  return 0; // cluster columns belong to head softmax
}

__device__ __forceinline__ unsigned pack2(float x, float y){
  __hip_bfloat16 a = __float2bfloat16(x);
  __hip_bfloat16 b = __float2bfloat16(y);
  unsigned short ua = *reinterpret_cast<unsigned short*>(&a);
  unsigned short ub = *reinterpret_cast<unsigned short*>(&b);
  return (unsigned)ua | ((unsigned)ub << 16);
}

#define BM 256
#define BN 128
#define BK 32
#define NTHREADS 512
#define KSTEPS (D_DIM/BK)   // 32
#define NPHASE (KSTEPS/2)   // 16 (2 K-steps per phase)
#define NCOLT 2092          // ceil(NEXT_/128)
#define NBLK 8384           // 8 XCD * 1048 (16 dead pad blocks)

#define APRIME_OFF 32768                      // byte offset of A' in ws
#define APRIME_BYTES (1024*1024*2)            // 2 MB bf16 fragment-ordered hidden

// direct global->LDS (16B/lane). Dest is wave-uniform base + lane*16 (m104);
// source address is per-lane.
__device__ __forceinline__ void stage16(const float* g, unsigned short* l){
  __builtin_amdgcn_global_load_lds(
      (const __attribute__((address_space(1))) void*)g,
      (__attribute__((address_space(3))) void*)l, 16, 0, 0);
}

// packed fp32x2 -> bf16x2 (single VALU op). Low half = x.
#define CVTPK(d, x, y) asm("v_cvt_pk_bf16_f32 %0, %1, %2" : "=v"(d) : "v"(x), "v"(y))

// Convert hidden (1024x1024 f32) -> A' bf16 in MFMA-fragment order:
// A'[rb(64)][kc(128)][r16(16)][e(8)]; wave frag load = 1024 contiguous bytes.
__global__ void prep_convert(const float* __restrict__ hidden,
                             unsigned short* __restrict__ Ap)
{
  int t = blockIdx.x * blockDim.x + threadIdx.x;   // 0..131071
  int r16 = t & 15, kc = (t >> 4) & 127, rb = t >> 11;
  const float4* src = reinterpret_cast<const float4*>(hidden + ((size_t)(rb*16 + r16) * D_DIM + kc*8));
  float4 x = src[0], y = src[1];
  uint4 o;
  o.x = pack2(x.x, x.y); o.y = pack2(x.z, x.w);
  o.z = pack2(y.x, y.y); o.w = pack2(y.z, y.w);
  reinterpret_cast<uint4*>(Ap)[t] = o;             // dst = t*16B: fully coalesced
}

// Per-(row, segment) sum of exp(logit + bias) into accg[row*8 + seg].
// FINAL (R21) = R16 verbatim — the measured optimum across 20 rounds (822 us):
//  - XCD remap: 4 row-blocks sharing a 128-col W strip -> same XCD (R5:
//    FETCH 2.25 GB -> 0.74 GB, most W reads are L2 hits).
//  - A pre-converted to bf16 in MFMA-fragment order (2 MB, L2-resident),
//    read direct-from-global per fragment — no A staging at all (R8).
//  - B staged fp32 via global_load_lds DMA (no reg round-trip, no producer
//    VALU), KC=2 phase double-buffering (32 KB buffers, 16 barriers total),
//    source-side chunk-XOR bank involution, consumer v_cvt_pk_bf16_f32.
//  - 16x16x32 MFMA (R17: 32x32 loses issue-slot latency hiding).
//  - <=64 arch VGPR -> 2 blocks/CU (the 128-reg cliff killed every deeper
//    pipeline: R4/R6/R7/R11/R14/R20 — TLP beats in-wave pipelining here).
__global__ __launch_bounds__(NTHREADS, 1) void gemm_lse_adir(
    const unsigned short* __restrict__ Ap, const float* __restrict__ W,
    const float* __restrict__ bias,   const float* __restrict__ cw,
    const float* __restrict__ cb,     float* __restrict__ accg)
{
  const int b = blockIdx.x;
  const int k8 = b & 7;                // XCD slot
  const int sq_ = b >> 3;              // sequence within XCD
  const int xb = sq_ & 3;              // row-block 0..3 (sharers adjacent)
  const int yb = (sq_ >> 2) * 8 + k8;  // col-strip
  if (yb >= NCOLT) return;             // pad blocks

  // B double buffer: TWO K-steps of fp32 as [s(2)][h(2)][row(128)][16f] = 32 KB each.
  __shared__ unsigned short lsB0[2 * BN * 64];   // 32 KB
  __shared__ unsigned short lsB1[2 * BN * 64];   // 32 KB

  const int tid = threadIdx.x;
  const int rowBase = xb * BM;
  const int colBase = yb * BN;

  const int lane = tid & 63;
  const int wv = tid >> 6;
  const int wm = wv >> 1;   // 0..3 : 64-row slab
  const int wn = wv & 1;    // 0..1 : 64-col slab
  const int q  = lane >> 4; // k-chunk
  const int r16 = lane & 15;

  // ---- B stage source pointer: wave wv covers rows wv*16..+16; lane ->
  // (row_local = lane>>2, dest chunk = lane&3); source chunk XOR'd (involution
  // with the read).
  const float* sp;
  {
    int srow = wv*16 + (lane >> 2);
    int c    = (lane & 3) ^ ((srow >> 1) & 3);
    int col  = colBase + srow;
    const float* base = (col < NTOK)  ? (W  + (size_t)col * D_DIM)
                      : (col < NEXT_) ? (cw + (size_t)(col - NTOK) * D_DIM) : W;
    sp = base + c*4;
  }
  const int dstH0 = wv*512;            // h=0 region within a step (ushort units)
  const int dstH1 = 4096 + wv*512;     // h=1 region within a step

  // stage one K-step kn into sub-buffer (kn&1) of Lbuf
#define STAGE1(Lbuf, kn) do{ \
    stage16(sp + (kn)*BK,      &Lbuf[((kn)&1)*8192 + dstH0]); \
    stage16(sp + (kn)*BK + 16, &Lbuf[((kn)&1)*8192 + dstH1]); }while(0)
#define STAGE2(Lbuf, kn) do{ STAGE1(Lbuf, kn); STAGE1(Lbuf, (kn)+1); }while(0)

  // ---- consumer B-fragment offsets (ushort units, within one step) ----
  int loO[4], hiO[4];
#pragma unroll
  for (int j=0;j<4;++j){
    int row = wn*64 + j*16 + r16;
    int swz = (row >> 1) & 3;
    int h   = q >> 1;
    loO[j] = h*4096 + row*32 + (((2*q  ) & 3) ^ swz)*8;
    hiO[j] = h*4096 + row*32 + (((2*q+1) & 3) ^ swz)*8;
  }

  // A' fragment pointers (ushort units): frag i at a_i + kt*512
  const unsigned short* a0 = Ap + (size_t)(xb*16 + wm*4 + 0)*16384 + q*128 + r16*8;
  const unsigned short* a1 = Ap + (size_t)(xb*16 + wm*4 + 1)*16384 + q*128 + r16*8;
  const unsigned short* a2 = Ap + (size_t)(xb*16 + wm*4 + 2)*16384 + q*128 + r16*8;
  const unsigned short* a3 = Ap + (size_t)(xb*16 + wm*4 + 3)*16384 + q*128 + r16*8;

  f32x4 acc[4][4];
#pragma unroll
  for (int i=0;i<4;++i)
#pragma unroll
    for (int j=0;j<4;++j) acc[i][j] = (f32x4){0.f,0.f,0.f,0.f};

#define BFRAG(Lp, j, out) { \
    float4 lo = *reinterpret_cast<const float4*>(&Lp[loO[j]]); \
    float4 hi = *reinterpret_cast<const float4*>(&Lp[hiO[j]]); \
    unsigned u0,u1,u2,u3; \
    CVTPK(u0, lo.x, lo.y); CVTPK(u1, lo.z, lo.w); \
    CVTPK(u2, hi.x, hi.y); CVTPK(u3, hi.z, hi.w); \
    uint4v uu; uu.x=u0; uu.y=u1; uu.z=u2; uu.w=u3; \
    out = __builtin_bit_cast(bf16x8, uu); }

  // one K-step: A frags direct from L2 + B frags from LDS sub-buffer + 16 MFMA
#define KSTEP(Lp, kt) do{ \
    bf16x8 af0 = *reinterpret_cast<const bf16x8*>(a0 + (kt)*512); \
    bf16x8 af1 = *reinterpret_cast<const bf16x8*>(a1 + (kt)*512); \
    bf16x8 af2 = *reinterpret_cast<const bf16x8*>(a2 + (kt)*512); \
    bf16x8 af3 = *reinterpret_cast<const bf16x8*>(a3 + (kt)*512); \
    bf16x8 b0, b1, b2, b3; \
    BFRAG(Lp, 0, b0); BFRAG(Lp, 1, b1); BFRAG(Lp, 2, b2); BFRAG(Lp, 3, b3); \
    acc[0][0] = __builtin_amdgcn_mfma_f32_16x16x32_bf16(af0, b0, acc[0][0], 0,0,0); \
    acc[0][1] = __builtin_amdgcn_mfma_f32_16x16x32_bf16(af0, b1, acc[0][1], 0,0,0); \
    acc[0][2] = __builtin_amdgcn_mfma_f32_16x16x32_bf16(af0, b2, acc[0][2], 0,0,0); \
    acc[0][3] = __builtin_amdgcn_mfma_f32_16x16x32_bf16(af0, b3, acc[0][3], 0,0,0); \
    acc[1][0] = __builtin_amdgcn_mfma_f32_16x16x32_bf16(af1, b0, acc[1][0], 0,0,0); \
    acc[1][1] = __builtin_amdgcn_mfma_f32_16x16x32_bf16(af1, b1, acc[1][1], 0,0,0); \
    acc[1][2] = __builtin_amdgcn_mfma_f32_16x16x32_bf16(af1, b2, acc[1][2], 0,0,0); \
    acc[1][3] = __builtin_amdgcn_mfma_f32_16x16x32_bf16(af1, b3, acc[1][3], 0,0,0); \
    acc[2][0] = __builtin_amdgcn_mfma_f32_16x16x32_bf16(af2, b0, acc[2][0], 0,0,0); \
    acc[2][1] = __builtin_amdgcn_mfma_f32_16x16x32_bf16(af2, b1, acc[2][1], 0,0,0); \
    acc[2][2] = __builtin_amdgcn_mfma_f32_16x16x32_bf16(af2, b2, acc[2][2], 0,0,0); \
    acc[2][3] = __builtin_amdgcn_mfma_f32_16x16x32_bf16(af2, b3, acc[2][3], 0,0,0); \
    acc[3][0] = __builtin_amdgcn_mfma_f32_16x16x32_bf16(af3, b0, acc[3][0], 0,0,0); \
    acc[3][1] = __builtin_amdgcn_mfma_f32_16x16x32_bf16(af3, b1, acc[3][1], 0,0,0); \
    acc[3][2] = __builtin_amdgcn_mfma_f32_16x16x32_bf16(af3, b2, acc[3][2], 0,0,0); \
    acc[3][3] = __builtin_amdgcn_mfma_f32_16x16x32_bf16(af3, b3, acc[3][3], 0,0,0); \
  }while(0)

  // ---- prologue: stage phase 0 (steps 0,1) into buf0 ----
  STAGE2(lsB0, 0);
  __syncthreads();   // vmcnt(0)+lgkmcnt(0) drain publishes the stage

  for (int p = 0; p < NPHASE; ++p){
    unsigned short* Lr = (p & 1) ? lsB1 : lsB0;
    unsigned short* Lw = (p & 1) ? lsB0 : lsB1;
    const int k0 = 2*p;

    if (p + 1 < NPHASE) STAGE2(Lw, k0+2);   // in flight across the whole phase

    KSTEP(Lr,          k0    );            // sub-step 0 (sub-buffer 0)
    KSTEP((Lr + 8192), k0 + 1);            // sub-step 1 (sub-buffer 1)

    __syncthreads();   // drains vmcnt(0): stage(p+1) complete & visible
  }

  // ---- fused epilogue: exp + segmented reduce + atomic ----
  int sq[4]; float bq[4];
#pragma unroll
  for (int f=0; f<4; ++f){
    int c = colBase + wn*64 + f*16 + r16;
    if (c < NTOK)       { sq[f] = seg_of(c); bq[f] = bias[c]; }
    else if (c < NEXT_) { sq[f] = 0;         bq[f] = cb[c - NTOK]; }
    else                { sq[f] = -1;        bq[f] = 0.f; }
  }
  int sfirst = seg_of(colBase);
  int clast  = colBase + BN - 1; if (clast > NEXT_-1) clast = NEXT_-1;
  int slast  = seg_of(clast);
  int smin = sfirst, smax = slast;
  if (slast < sfirst){ smin = 0; smax = 4; }   // wrap tile at N_TOKEN boundary

#pragma unroll
  for (int i=0;i<4;++i){
#pragma unroll
    for (int r=0;r<4;++r){
      float e[4];
#pragma unroll
      for (int f=0;f<4;++f) e[f] = __expf(acc[i][f][r] + bq[f]);
      int rowg = rowBase + wm*64 + i*16 + (lane>>4)*4 + r;   // C/D: row=(l>>4)*4+reg
      for (int s2 = smin; s2 <= smax; ++s2){
        float p2 = 0.f;
#pragma unroll
        for (int f=0;f<4;++f) p2 += (sq[f]==s2) ? e[f] : 0.f;
#pragma unroll
        for (int off=1; off<16; off<<=1) p2 += __shfl_xor(p2, off, 16);
        if ((lane & 15) == 0 && p2 != 0.f) atomicAdd(&accg[rowg*8 + s2], p2);
      }
    }
  }
}

// One wave per row: target logit + routing logit + final nll.
__global__ __launch_bounds__(256) void finalize_kernel(
    const float* __restrict__ hidden, const int* __restrict__ target,
    const float* __restrict__ W,      const float* __restrict__ bias,
    const float* __restrict__ cw,     const float* __restrict__ cb,
    const float* __restrict__ accg,   float* __restrict__ out)
{
  const int row  = blockIdx.x * 4 + (threadIdx.x >> 6);
  const int lane = threadIdx.x & 63;
  const int t = target[row];

  const float4* h4 = reinterpret_cast<const float4*>(hidden + (size_t)row * D_DIM);
  const float4* w1 = reinterpret_cast<const float4*>(W + (size_t)t * D_DIM);
  int s = 0; const float* jraw = W; float jb = 0.f;
  if (t >= HEADN){
    if      (t < 20008)  { s=1; jraw = W;          jb = bias[0]; }  // j = 0
    else if (t < 20016)  { s=2; jraw = W + D_DIM;  jb = bias[1]; }  // j = 1
    else if (t < 200000) { s=3; jraw = cw + D_DIM; jb = cb[1];   }  // j = 20001 -> cluster 1
    else                 { s=4; jraw = cw;         jb = cb[0];   }  // j = 20000 -> cluster 0
  }
  const float4* w2 = reinterpret_cast<const float4*>(jraw);

  float p1 = 0.f, p2 = 0.f;
#pragma unroll
  for (int j=0;j<4;++j){
    float4 hv = h4[lane + 64*j];
    float4 av = w1[lane + 64*j];
    float4 bv = w2[lane + 64*j];
    p1 += hv.x*av.x + hv.y*av.y + hv.z*av.z + hv.w*av.w;
    p2 += hv.x*bv.x + hv.y*bv.y + hv.z*bv.z + hv.w*bv.w;
  }
#pragma unroll
  for (int off=32; off; off>>=1){
    p1 += __shfl_xor(p1, off, 64);
    p2 += __shfl_xor(p2, off, 64);
  }

  if (lane == 0){
    float lseH = __logf(accg[row*8 + 0]);
    float nll;
    if (t < HEADN){
      nll = -(p1 + bias[t] - lseH);
    } else {
      float lseS = __logf(accg[row*8 + s]);
      nll = -((p2 + jb - lseH) + (p1 + bias[t] - lseS));
    }
    out[row] = nll;
  }
}

extern "C" void kernel_launch(void* const* d_in, const int* in_sizes, int n_in,
                              void* d_out, int out_size, void* d_ws, size_t ws_size,
                              hipStream_t stream)
{
  const float* hidden = (const float*)d_in[0];
  const int*   target = (const int*)  d_in[1];
  const float* W      = (const float*)d_in[2];
  const float* bias   = (const float*)d_in[3];
  const float* cw     = (const float*)d_in[4];
  const float* cb     = (const float*)d_in[5];
  float* out  = (float*)d_out;
  float* accg = (float*)d_ws;          // [1024][8] fp32 sum-of-exp accumulators
  unsigned short* Ap = (unsigned short*)((char*)d_ws + APRIME_OFF);

  hipMemsetAsync(accg, 0, 1024*8*sizeof(float), stream);

  prep_convert<<<512, 256, 0, stream>>>(hidden, Ap);
  gemm_lse_adir<<<NBLK, NTHREADS, 0, stream>>>(Ap, W, bias, cw, cb, accg);
  finalize_kernel<<<256, 256, 0, stream>>>(hidden, target, W, bias, cw, cb, accg, out);
}